// Round 13
// baseline (586.339 us; speedup 1.0000x reference)
//
#include <hip/hip_runtime.h>
#include <math.h>

#define PI_LEN 0.3141592653589793f   // pi / 10.0
#define LEN_F  10.0f
#define TBL    4096                   // table rows = TBL+1

__device__ __forceinline__ float fsilu(float x) {
  return x * __builtin_amdgcn_rcpf(1.f + __expf(-x));
}

// ---------------------------------------------------------------------------
// hist: deg[dst]++
// ---------------------------------------------------------------------------
__global__ __launch_bounds__(256) void hist_kernel(const int* __restrict__ ei,
                                                   int* __restrict__ deg, int E_) {
  int e = blockIdx.x * 256 + threadIdx.x;
  if (e < E_) atomicAdd(&deg[ei[E_ + e]], 1);
}

// ---------------------------------------------------------------------------
// tbl role helper (32 t-rows / 1024-thread block; half-wave-private LDS rows)
// ---------------------------------------------------------------------------
__device__ __forceinline__ void tbl_role(
    int i, int g, int t,
    const float* __restrict__ w1, const float* __restrict__ b1,
    const float* __restrict__ w2, const float* __restrict__ b2,
    float4* __restrict__ tbl4, float (*pe)[32], float (*hl)[32])
{
  bool okt = (t <= TBL);
  float d = (float)t * (LEN_F / (float)TBL);
  pe[i][g] = (g < 16) ? __sinf(d * (float)(g + 1) * PI_LEN)
                      : __cosf(d * (float)(g - 15) * PI_LEN);
  float h = b1[g];
  for (int k = 0; k < 32; ++k) h += pe[i][k] * w1[k*32 + g];
  hl[i][g] = fsilu(h);
  float o0 = b2[g], o1 = b2[32+g], o2 = b2[64+g], o3 = b2[96+g];
  for (int k = 0; k < 32; ++k) {
    float hk = hl[i][k];
    o0 += hk * w2[k*128 +      g];
    o1 += hk * w2[k*128 + 32 + g];
    o2 += hk * w2[k*128 + 64 + g];
    o3 += hk * w2[k*128 + 96 + g];
  }
  if (okt) tbl4[(long)t*32 + g] = make_float4(o0, o1, o2, o3);
}

// ---------------------------------------------------------------------------
// scan + prep roles in ONE launch:
//   block 0       -> exclusive scan of deg -> off, cursor
//   next nodeB32  -> nodeA(l0): Aout4a from s_in
//   next tblB32   -> filter table l0
//   next tblB32   -> filter table l1
// ---------------------------------------------------------------------------
__global__ __launch_bounds__(1024) void scan_prep_kernel(
    const int* __restrict__ deg, int* __restrict__ off,
    int* __restrict__ cursor, int N_,
    const float* __restrict__ s,
    const float* __restrict__ mpw1, const float* __restrict__ mpb1,
    const float* __restrict__ mpw2, const float* __restrict__ mpb2,
    const float* __restrict__ mww1a, const float* __restrict__ mwb1a,
    const float* __restrict__ mww2a, const float* __restrict__ mwb2a,
    const float* __restrict__ mww1b, const float* __restrict__ mwb1b,
    const float* __restrict__ mww2b, const float* __restrict__ mwb2b,
    float4* __restrict__ Aout4a, float4* __restrict__ tbl4a,
    float4* __restrict__ tbl4b, int nodeB32, int tblB32)
{
  __shared__ float xs[32][32];
  __shared__ float hs[32][32];
  __shared__ int wtot[16];
  __shared__ int carry_s;
  int bid = blockIdx.x;
  int tid = threadIdx.x;
  if (bid == 0) {                            // ---- scan role ----
    int lane = tid & 63, wid = tid >> 6;
    if (tid == 0) carry_s = 0;
    __syncthreads();
    int nch = (N_ + 8191) / 8192;
    for (int c = 0; c < nch; ++c) {
      int base_idx = c * 8192 + tid * 8;
      int x[8]; int mysum = 0;
      #pragma unroll
      for (int j = 0; j < 8; ++j) { int idx = base_idx + j; x[j] = (idx < N_) ? deg[idx] : 0; mysum += x[j]; }
      int incl = mysum;
      #pragma unroll
      for (int st = 1; st < 64; st <<= 1) { int t = __shfl_up(incl, st, 64); if (lane >= st) incl += t; }
      if (lane == 63) wtot[wid] = incl;
      __syncthreads();
      if (wid == 0) {
        int wt = (lane < 16) ? wtot[lane] : 0;
        #pragma unroll
        for (int st = 1; st < 16; st <<= 1) { int t = __shfl_up(wt, st, 64); if (lane >= st) wt += t; }
        if (lane < 16) wtot[lane] = wt;
      }
      __syncthreads();
      int wexcl = (wid > 0) ? wtot[wid - 1] : 0;
      int run = carry_s + wexcl + (incl - mysum);
      #pragma unroll
      for (int j = 0; j < 8; ++j) {
        int idx = base_idx + j;
        if (idx < N_) { off[idx] = run; cursor[idx] = run; }
        run += x[j];
      }
      __syncthreads();
      if (tid == 0) carry_s += wtot[15];
      __syncthreads();
    }
    if (tid == 0) off[N_] = carry_s;
    return;
  }
  bid -= 1;
  int i = tid >> 5, g = tid & 31;
  if (bid < nodeB32) {                       // ---- nodeA(l0) role ----
    long n = (long)bid * 32 + i;
    bool ok = (n < N_);
    xs[i][g] = ok ? s[n*32 + g] : 0.f;
    float h = mpb1[g];
    for (int k = 0; k < 32; ++k) h += xs[i][k] * mpw1[k*32 + g];
    hs[i][g] = fsilu(h);
    float o0 = mpb2[g], o1 = mpb2[32+g], o2 = mpb2[64+g], o3 = mpb2[96+g];
    for (int k = 0; k < 32; ++k) {
      float hk = hs[i][k];
      o0 += hk * mpw2[k*128 +      g];
      o1 += hk * mpw2[k*128 + 32 + g];
      o2 += hk * mpw2[k*128 + 64 + g];
      o3 += hk * mpw2[k*128 + 96 + g];
    }
    if (ok) Aout4a[n*32 + g] = make_float4(o0, o1, o2, o3 * xs[i][g]);
    return;
  }
  bid -= nodeB32;
  if (bid < tblB32) {                        // ---- tbl l0 role ----
    tbl_role(i, g, bid * 32 + i, mww1a, mwb1a, mww2a, mwb2a, tbl4a, xs, hs);
    return;
  }
  bid -= tblB32;                             // ---- tbl l1 role ----
  tbl_role(i, g, bid * 32 + i, mww1b, mwb1b, mww2b, mwb2b, tbl4b, xs, hs);
}

// ---------------------------------------------------------------------------
// scatter: CSR data perm (after scan)
// ---------------------------------------------------------------------------
__global__ __launch_bounds__(256) void scatter_kernel(
    const int* __restrict__ ei, const float* __restrict__ dist,
    const float* __restrict__ edir, int* __restrict__ cursor,
    int* __restrict__ srcp, float4* __restrict__ edata, int E_) {
  int e = blockIdx.x * 256 + threadIdx.x;
  if (e < E_) {
    int dst = ei[E_ + e];
    int pos = atomicAdd(&cursor[dst], 1);
    srcp[pos] = ei[e];
    edata[pos] = make_float4(edir[3*e], edir[3*e+1], edir[3*e+2], dist[e]);
  }
}

// ---------------------------------------------------------------------------
// gather: EXACT round-4 proven shape (56 VGPR, no LDS, no barriers).
// 4 nodes/block, one wave64/node, 4 edges per half-wave batched.
// ---------------------------------------------------------------------------
#define EDGE_MATH(ED, M0, M1, FR, Av, V0, V1, V2)                         \
  {                                                                        \
    float ga = M0.x + FR*(M1.x - M0.x);                                    \
    float ca = M0.y + FR*(M1.y - M0.y);                                    \
    float da = M0.z + FR*(M1.z - M0.z);                                    \
    float sa = M0.w + FR*(M1.w - M0.w);                                    \
    float gates = ga*Av.x, cpg = ca*Av.y, sed = da*Av.z;                   \
    acc_s += sa*Av.w;                                                      \
    float crx = ED.y*vd2 - ED.z*vd1;                                       \
    float cry = ED.z*vd0 - ED.x*vd2;                                       \
    float crz = ED.x*vd1 - ED.y*vd0;                                       \
    av0 += sed*ED.x + gates*V0 + cpg*crx;                                  \
    av1 += sed*ED.y + gates*V1 + cpg*cry;                                  \
    av2 += sed*ED.z + gates*V2 + cpg*crz;                                  \
  }

__global__ __launch_bounds__(256) void gather_kernel(
    const int* __restrict__ off, const int* __restrict__ srcp,
    const float4* __restrict__ edata, const float4* __restrict__ tbl4,
    const float* __restrict__ v_prev, const float4* __restrict__ Aout4,
    float4* __restrict__ acc4, int N_)
{
  int tid = threadIdx.x, w = tid >> 6, lane = tid & 63, g = lane & 31, hf = lane >> 5;
  int n = blockIdx.x * 4 + w;
  if (n >= N_) return;
  const float* vp = v_prev + (long)n*96 + g*3;
  float vd0 = vp[0], vd1 = vp[1], vd2 = vp[2];
  int pstart = off[n], pend = off[n + 1];
  float acc_s = 0, av0 = 0, av1 = 0, av2 = 0;
  const float inv_step = (float)TBL / LEN_F;

  int deg = pend - pstart;
  int nfull = deg >> 3;
  int pb = pstart + hf * 4;
  for (int it = 0; it < nfull; ++it, pb += 8) {
    int srcs[4]; float4 ed[4];
    #pragma unroll
    for (int b = 0; b < 4; ++b) { srcs[b] = srcp[pb + b]; ed[b] = edata[pb + b]; }
    float4 m0[4], m1[4], A[4]; float fr[4];
    float vs0[4], vs1[4], vs2[4];
    #pragma unroll
    for (int b = 0; b < 4; ++b) {
      float x = ed[b].w * inv_step;
      float f = floorf(x);
      int i0 = (int)f; if (i0 > TBL - 1) i0 = TBL - 1;
      fr[b] = x - f;
      m0[b] = tbl4[(long)i0*32 + g];
      m1[b] = tbl4[(long)(i0 + 1)*32 + g];
      A[b]  = Aout4[(long)srcs[b]*32 + g];
      const float* vq = v_prev + (long)srcs[b]*96 + g*3;
      vs0[b] = vq[0]; vs1[b] = vq[1]; vs2[b] = vq[2];
    }
    #pragma unroll
    for (int b = 0; b < 4; ++b)
      EDGE_MATH(ed[b], m0[b], m1[b], fr[b], A[b], vs0[b], vs1[b], vs2[b]);
  }
  int p = pstart + nfull * 8 + hf;
  for (; p + 2 < pend; p += 4) {
    int  s0_ = srcp[p], s1_ = srcp[p + 2];
    float4 e0 = edata[p], e1 = edata[p + 2];
    float x0 = e0.w * inv_step, x1 = e1.w * inv_step;
    float f0 = floorf(x0), f1 = floorf(x1);
    int i0 = (int)f0; if (i0 > TBL - 1) i0 = TBL - 1;
    int i1 = (int)f1; if (i1 > TBL - 1) i1 = TBL - 1;
    float r0 = x0 - f0, r1 = x1 - f1;
    float4 a0 = tbl4[(long)i0*32 + g], b0 = tbl4[(long)(i0+1)*32 + g];
    float4 a1 = tbl4[(long)i1*32 + g], b1 = tbl4[(long)(i1+1)*32 + g];
    float4 A0 = Aout4[(long)s0_*32 + g], A1 = Aout4[(long)s1_*32 + g];
    const float* vq0 = v_prev + (long)s0_*96 + g*3;
    const float* vq1 = v_prev + (long)s1_*96 + g*3;
    float u0 = vq0[0], u1 = vq0[1], u2 = vq0[2];
    float t0 = vq1[0], t1 = vq1[1], t2 = vq1[2];
    EDGE_MATH(e0, a0, b0, r0, A0, u0, u1, u2);
    EDGE_MATH(e1, a1, b1, r1, A1, t0, t1, t2);
  }
  if (p < pend) {
    int  s0_ = srcp[p];
    float4 e0 = edata[p];
    float x0 = e0.w * inv_step;
    float f0 = floorf(x0);
    int i0 = (int)f0; if (i0 > TBL - 1) i0 = TBL - 1;
    float r0 = x0 - f0;
    float4 a0 = tbl4[(long)i0*32 + g], b0 = tbl4[(long)(i0+1)*32 + g];
    float4 A0 = Aout4[(long)s0_*32 + g];
    const float* vq0 = v_prev + (long)s0_*96 + g*3;
    float u0 = vq0[0], u1 = vq0[1], u2 = vq0[2];
    EDGE_MATH(e0, a0, b0, r0, A0, u0, u1, u2);
  }
  av0   += __shfl_xor(av0, 32);
  av1   += __shfl_xor(av1, 32);
  av2   += __shfl_xor(av2, 32);
  acc_s += __shfl_xor(acc_s, 32);
  if (hf == 0) acc4[(long)n*32 + g] = make_float4(av0, av1, av2, acc_s);
}

// ---------------------------------------------------------------------------
// update kernels: r11 proven shape — 2 nodes per wave, weight loads shared
// x2 via dual accumulation, k-split across halves + shfl_xor(32),
// barrier-free per-wave LDS rows. NEW: v-arrays padded to stride-4 (16B) so
// phase-1 and readout read one broadcast ds_read_b128 per k per node.
// ---------------------------------------------------------------------------
__global__ __launch_bounds__(256) void update_mid_kernel(
    const float* __restrict__ s_prev, const float* __restrict__ v_prev,
    const float4* __restrict__ acc4,
    const float* __restrict__ uU, const float* __restrict__ uV,
    const float* __restrict__ uw1, const float* __restrict__ ub1,
    const float* __restrict__ uw2, const float* __restrict__ ub2,
    const float* __restrict__ nw1, const float* __restrict__ nb1,
    const float* __restrict__ nw2, const float* __restrict__ nb2,
    float* __restrict__ s_out, float* __restrict__ v_out,
    float4* __restrict__ Aout4b, int N_)
{
  __shared__ __align__(16) float vA_[4][128], vB_[4][128];
  __shared__ float inA[4][64], inB[4][64];
  __shared__ float hA_[4][32], hB_[4][32];
  int tid = threadIdx.x, w = tid >> 6, lane = tid & 63, g = lane & 31, hf = lane >> 5;
  long nown = (long)blockIdx.x * 8 + 2*w + hf;
  bool ok = (nown < N_);
  float nv0 = 0, nv1 = 0, nv2 = 0, ns = 0;
  if (ok) {
    float4 a = acc4[nown*32 + g];
    const float* vp = v_prev + nown*96 + g*3;
    nv0 = vp[0] + a.x; nv1 = vp[1] + a.y; nv2 = vp[2] + a.z;
    ns  = s_prev[nown*32 + g] + a.w;
  }
  if (hf == 0) {
    vA_[w][g*4+0] = nv0; vA_[w][g*4+1] = nv1; vA_[w][g*4+2] = nv2; vA_[w][g*4+3] = 0.f;
    inA[w][32+g] = ns;
  } else {
    vB_[w][g*4+0] = nv0; vB_[w][g*4+1] = nv1; vB_[w][g*4+2] = nv2; vB_[w][g*4+3] = 0.f;
    inB[w][32+g] = ns;
  }
  float VvA0=0,VvA1=0,VvA2=0,UvA0=0,UvA1=0,UvA2=0;
  float VvB0=0,VvB1=0,VvB2=0,UvB0=0,UvB1=0,UvB2=0;
  for (int j = 0; j < 16; ++j) {
    int k = hf*16 + j;
    float wv = uV[k*32 + g], wu = uU[k*32 + g];
    float4 a4 = *(const float4*)&vA_[w][k*4];
    float4 b4 = *(const float4*)&vB_[w][k*4];
    VvA0 += a4.x*wv; VvA1 += a4.y*wv; VvA2 += a4.z*wv;
    UvA0 += a4.x*wu; UvA1 += a4.y*wu; UvA2 += a4.z*wu;
    VvB0 += b4.x*wv; VvB1 += b4.y*wv; VvB2 += b4.z*wv;
    UvB0 += b4.x*wu; UvB1 += b4.y*wu; UvB2 += b4.z*wu;
  }
  VvA0 += __shfl_xor(VvA0,32); VvA1 += __shfl_xor(VvA1,32); VvA2 += __shfl_xor(VvA2,32);
  UvA0 += __shfl_xor(UvA0,32); UvA1 += __shfl_xor(UvA1,32); UvA2 += __shfl_xor(UvA2,32);
  VvB0 += __shfl_xor(VvB0,32); VvB1 += __shfl_xor(VvB1,32); VvB2 += __shfl_xor(VvB2,32);
  UvB0 += __shfl_xor(UvB0,32); UvB1 += __shfl_xor(UvB1,32); UvB2 += __shfl_xor(UvB2,32);
  float VnA = sqrtf(VvA0*VvA0 + VvA1*VvA1 + VvA2*VvA2);
  float VnB = sqrtf(VvB0*VvB0 + VvB1*VvB1 + VvB2*VvB2);
  float Vno = hf ? VnB : VnA;
  float Uv0 = hf ? UvB0 : UvA0, Uv1 = hf ? UvB1 : UvA1, Uv2 = hf ? UvB2 : UvA2;
  if (hf == 0) inA[w][g] = VnA; else inB[w][g] = VnB;
  float hAa = 0, hBb = 0;
  for (int j = 0; j < 32; ++j) {
    int k = hf*32 + j;
    float wk = uw1[k*32 + g];
    hAa += inA[w][k]*wk; hBb += inB[w][k]*wk;
  }
  hAa += __shfl_xor(hAa, 32); hBb += __shfl_xor(hBb, 32);
  float bb1 = ub1[g];
  hAa = fsilu(hAa + bb1); hBb = fsilu(hBb + bb1);
  if (hf == 0) hA_[w][g] = hAa; else hB_[w][g] = hBb;
  float ogA=0, osA=0, oaA=0, ogB=0, osB=0, oaB=0;
  for (int j = 0; j < 16; ++j) {
    int k = hf*16 + j;
    float w0 = uw2[k*96 + g], w1 = uw2[k*96 + 32 + g], w2 = uw2[k*96 + 64 + g];
    float ha = hA_[w][k], hb = hB_[w][k];
    ogA += ha*w0; osA += ha*w1; oaA += ha*w2;
    ogB += hb*w0; osB += hb*w1; oaB += hb*w2;
  }
  ogA += __shfl_xor(ogA,32); osA += __shfl_xor(osA,32); oaA += __shfl_xor(oaA,32);
  ogB += __shfl_xor(ogB,32); osB += __shfl_xor(osB,32); oaB += __shfl_xor(oaB,32);
  float og_o = (hf ? ogB : ogA) + ub2[g];
  float os_o = (hf ? osB : osA) + ub2[32 + g];
  float oa_o = (hf ? oaB : oaA) + ub2[64 + g];
  float sfin = ns + Vno*Vno*os_o + oa_o;
  if (ok) {
    float* vo = v_out + nown*96 + g*3;
    vo[0] = nv0 + og_o*Uv0;
    vo[1] = nv1 + og_o*Uv1;
    vo[2] = nv2 + og_o*Uv2;
    s_out[nown*32 + g] = sfin;
  }
  if (hf == 0) inA[w][g] = sfin; else inB[w][g] = sfin;
  float h2A = 0, h2B = 0;
  for (int j = 0; j < 16; ++j) {
    int k = hf*16 + j;
    float wk = nw1[k*32 + g];
    h2A += inA[w][k]*wk; h2B += inB[w][k]*wk;
  }
  h2A += __shfl_xor(h2A, 32); h2B += __shfl_xor(h2B, 32);
  float nb1g = nb1[g];
  h2A = fsilu(h2A + nb1g); h2B = fsilu(h2B + nb1g);
  if (hf == 0) hA_[w][g] = h2A; else hB_[w][g] = h2B;
  float o0A=0,o1A=0,o2A=0,o3A=0, o0B=0,o1B=0,o2B=0,o3B=0;
  for (int j = 0; j < 16; ++j) {
    int k = hf*16 + j;
    float w0 = nw2[k*128 + g],      w1 = nw2[k*128 + 32 + g];
    float w2 = nw2[k*128 + 64 + g], w3 = nw2[k*128 + 96 + g];
    float ha = hA_[w][k], hb = hB_[w][k];
    o0A += ha*w0; o1A += ha*w1; o2A += ha*w2; o3A += ha*w3;
    o0B += hb*w0; o1B += hb*w1; o2B += hb*w2; o3B += hb*w3;
  }
  o0A += __shfl_xor(o0A,32); o1A += __shfl_xor(o1A,32);
  o2A += __shfl_xor(o2A,32); o3A += __shfl_xor(o3A,32);
  o0B += __shfl_xor(o0B,32); o1B += __shfl_xor(o1B,32);
  o2B += __shfl_xor(o2B,32); o3B += __shfl_xor(o3B,32);
  float o0o = (hf ? o0B : o0A) + nb2[g];
  float o1o = (hf ? o1B : o1A) + nb2[32 + g];
  float o2o = (hf ? o2B : o2A) + nb2[64 + g];
  float o3o = (hf ? o3B : o3A) + nb2[96 + g];
  if (ok) Aout4b[nown*32 + g] = make_float4(o0o, o1o, o2o, o3o * sfin);
}

__global__ __launch_bounds__(256) void update_fin_kernel(
    const float* __restrict__ s_prev, const float* __restrict__ v_prev,
    const float4* __restrict__ acc4,
    const float* __restrict__ uU, const float* __restrict__ uV,
    const float* __restrict__ uw1, const float* __restrict__ ub1,
    const float* __restrict__ uw2, const float* __restrict__ ub2,
    const float* __restrict__ rw1, const float* __restrict__ rb1,
    const float* __restrict__ rw2, const float* __restrict__ rb2,
    const float* __restrict__ roV, float* __restrict__ out, int N_)
{
  __shared__ __align__(16) float vA_[4][128], vB_[4][128];
  __shared__ float inA[4][64], inB[4][64];
  __shared__ float hA_[4][32], hB_[4][32];
  int tid = threadIdx.x, w = tid >> 6, lane = tid & 63, g = lane & 31, hf = lane >> 5;
  long nown = (long)blockIdx.x * 8 + 2*w + hf;
  bool ok = (nown < N_);
  float nv0 = 0, nv1 = 0, nv2 = 0, ns = 0;
  if (ok) {
    float4 a = acc4[nown*32 + g];
    const float* vp = v_prev + nown*96 + g*3;
    nv0 = vp[0] + a.x; nv1 = vp[1] + a.y; nv2 = vp[2] + a.z;
    ns  = s_prev[nown*32 + g] + a.w;
  }
  if (hf == 0) {
    vA_[w][g*4+0] = nv0; vA_[w][g*4+1] = nv1; vA_[w][g*4+2] = nv2; vA_[w][g*4+3] = 0.f;
    inA[w][32+g] = ns;
  } else {
    vB_[w][g*4+0] = nv0; vB_[w][g*4+1] = nv1; vB_[w][g*4+2] = nv2; vB_[w][g*4+3] = 0.f;
    inB[w][32+g] = ns;
  }
  float VvA0=0,VvA1=0,VvA2=0,UvA0=0,UvA1=0,UvA2=0;
  float VvB0=0,VvB1=0,VvB2=0,UvB0=0,UvB1=0,UvB2=0;
  for (int j = 0; j < 16; ++j) {
    int k = hf*16 + j;
    float wv = uV[k*32 + g], wu = uU[k*32 + g];
    float4 a4 = *(const float4*)&vA_[w][k*4];
    float4 b4 = *(const float4*)&vB_[w][k*4];
    VvA0 += a4.x*wv; VvA1 += a4.y*wv; VvA2 += a4.z*wv;
    UvA0 += a4.x*wu; UvA1 += a4.y*wu; UvA2 += a4.z*wu;
    VvB0 += b4.x*wv; VvB1 += b4.y*wv; VvB2 += b4.z*wv;
    UvB0 += b4.x*wu; UvB1 += b4.y*wu; UvB2 += b4.z*wu;
  }
  VvA0 += __shfl_xor(VvA0,32); VvA1 += __shfl_xor(VvA1,32); VvA2 += __shfl_xor(VvA2,32);
  UvA0 += __shfl_xor(UvA0,32); UvA1 += __shfl_xor(UvA1,32); UvA2 += __shfl_xor(UvA2,32);
  VvB0 += __shfl_xor(VvB0,32); VvB1 += __shfl_xor(VvB1,32); VvB2 += __shfl_xor(VvB2,32);
  UvB0 += __shfl_xor(UvB0,32); UvB1 += __shfl_xor(UvB1,32); UvB2 += __shfl_xor(UvB2,32);
  float VnA = sqrtf(VvA0*VvA0 + VvA1*VvA1 + VvA2*VvA2);
  float VnB = sqrtf(VvB0*VvB0 + VvB1*VvB1 + VvB2*VvB2);
  float Vno = hf ? VnB : VnA;
  float Uv0 = hf ? UvB0 : UvA0, Uv1 = hf ? UvB1 : UvA1, Uv2 = hf ? UvB2 : UvA2;
  if (hf == 0) inA[w][g] = VnA; else inB[w][g] = VnB;
  float hAa = 0, hBb = 0;
  for (int j = 0; j < 32; ++j) {
    int k = hf*32 + j;
    float wk = uw1[k*32 + g];
    hAa += inA[w][k]*wk; hBb += inB[w][k]*wk;
  }
  hAa += __shfl_xor(hAa, 32); hBb += __shfl_xor(hBb, 32);
  float bb1 = ub1[g];
  hAa = fsilu(hAa + bb1); hBb = fsilu(hBb + bb1);
  if (hf == 0) hA_[w][g] = hAa; else hB_[w][g] = hBb;
  float ogA=0, osA=0, oaA=0, ogB=0, osB=0, oaB=0;
  for (int j = 0; j < 16; ++j) {
    int k = hf*16 + j;
    float w0 = uw2[k*96 + g], w1 = uw2[k*96 + 32 + g], w2 = uw2[k*96 + 64 + g];
    float ha = hA_[w][k], hb = hB_[w][k];
    ogA += ha*w0; osA += ha*w1; oaA += ha*w2;
    ogB += hb*w0; osB += hb*w1; oaB += hb*w2;
  }
  ogA += __shfl_xor(ogA,32); osA += __shfl_xor(osA,32); oaA += __shfl_xor(oaA,32);
  ogB += __shfl_xor(ogB,32); osB += __shfl_xor(osB,32); oaB += __shfl_xor(oaB,32);
  float og_o = (hf ? ogB : ogA) + ub2[g];
  float os_o = (hf ? osB : osA) + ub2[32 + g];
  float oa_o = (hf ? oaB : oaA) + ub2[64 + g];
  float sfin = ns + Vno*Vno*os_o + oa_o;
  float vf0 = nv0 + og_o*Uv0, vf1 = nv1 + og_o*Uv1, vf2 = nv2 + og_o*Uv2;
  if (hf == 0) {
    vA_[w][g*4+0] = vf0; vA_[w][g*4+1] = vf1; vA_[w][g*4+2] = vf2;
    inA[w][g] = sfin;
  } else {
    vB_[w][g*4+0] = vf0; vB_[w][g*4+1] = vf1; vB_[w][g*4+2] = vf2;
    inB[w][g] = sfin;
  }
  float h2A = 0, h2B = 0;
  for (int j = 0; j < 16; ++j) {
    int k = hf*16 + j;
    float wk = rw1[k*32 + g];
    h2A += inA[w][k]*wk; h2B += inB[w][k]*wk;
  }
  h2A += __shfl_xor(h2A, 32); h2B += __shfl_xor(h2B, 32);
  float rb1g = rb1[g];
  h2A = fsilu(h2A + rb1g); h2B = fsilu(h2B + rb1g);
  if (hf == 0) hA_[w][g] = h2A; else hB_[w][g] = h2B;
  float invA=0, gateA=0, invB=0, gateB=0;
  for (int j = 0; j < 16; ++j) {
    int k = hf*16 + j;
    float w0 = rw2[k*64 + g], w1 = rw2[k*64 + 32 + g];
    float ha = hA_[w][k], hb = hB_[w][k];
    invA += ha*w0; gateA += ha*w1;
    invB += hb*w0; gateB += hb*w1;
  }
  float R0A=0,R1A=0,R2A=0, R0B=0,R1B=0,R2B=0;
  for (int j = 0; j < 16; ++j) {
    int k = hf*16 + j;
    float wk = roV[k*32 + g];
    float4 a4 = *(const float4*)&vA_[w][k*4];
    float4 b4 = *(const float4*)&vB_[w][k*4];
    R0A += a4.x*wk; R1A += a4.y*wk; R2A += a4.z*wk;
    R0B += b4.x*wk; R1B += b4.y*wk; R2B += b4.z*wk;
  }
  invA += __shfl_xor(invA,32); gateA += __shfl_xor(gateA,32);
  invB += __shfl_xor(invB,32); gateB += __shfl_xor(gateB,32);
  R0A += __shfl_xor(R0A,32); R1A += __shfl_xor(R1A,32); R2A += __shfl_xor(R2A,32);
  R0B += __shfl_xor(R0B,32); R1B += __shfl_xor(R1B,32); R2B += __shfl_xor(R2B,32);
  float inv_o  = (hf ? invB  : invA)  + rb2[g];
  float gate_o = (hf ? gateB : gateA) + rb2[32 + g];
  float R0o = hf ? R0B : R0A, R1o = hf ? R1B : R1A, R2o = hf ? R2B : R2A;
  if (ok) {
    out[nown*32 + g] = inv_o;
    long eb = (long)N_*32 + nown*96 + (long)g*3;
    out[eb+0] = gate_o*R0o; out[eb+1] = gate_o*R1o; out[eb+2] = gate_o*R2o;
  }
}

// ---------------------------------------------------------------------------
extern "C" void kernel_launch(void* const* d_in, const int* in_sizes, int n_in,
                              void* d_out, int out_size, void* d_ws, size_t ws_size,
                              hipStream_t stream)
{
  const float* s_in  = (const float*)d_in[0];
  const float* v_in  = (const float*)d_in[1];   // (N, F, 3)
  const int*   ei    = (const int*)  d_in[2];
  const float* dist  = (const float*)d_in[3];
  const float* edir  = (const float*)d_in[4];
  const float* mp_w1 = (const float*)d_in[5];
  const float* mp_b1 = (const float*)d_in[6];
  const float* mp_w2 = (const float*)d_in[7];
  const float* mp_b2 = (const float*)d_in[8];
  const float* mw_w1 = (const float*)d_in[9];
  const float* mw_b1 = (const float*)d_in[10];
  const float* mw_w2 = (const float*)d_in[11];
  const float* mw_b2 = (const float*)d_in[12];
  const float* u_U   = (const float*)d_in[13];
  const float* u_V   = (const float*)d_in[14];
  const float* u_w1  = (const float*)d_in[15];
  const float* u_b1  = (const float*)d_in[16];
  const float* u_w2  = (const float*)d_in[17];
  const float* u_b2  = (const float*)d_in[18];
  const float* ro_w1 = (const float*)d_in[19];
  const float* ro_b1 = (const float*)d_in[20];
  const float* ro_w2 = (const float*)d_in[21];
  const float* ro_b2 = (const float*)d_in[22];
  const float* ro_V  = (const float*)d_in[23];

  int N_ = in_sizes[0] / 32;
  int E_ = in_sizes[3];

  float*  sB    = (float*)d_ws;                       // N*32
  float*  vB    = sB + (size_t)N_*32;                 // N*96
  float4* Aout4a= (float4*)(vB + (size_t)N_*96);      // N*32 float4
  float4* Aout4b= Aout4a + (size_t)N_*32;             // N*32 float4
  float4* acc4b = Aout4b + (size_t)N_*32;             // N*32 float4
  float4* tbl4a = acc4b + (size_t)N_*32;              // (TBL+1)*32 float4
  float4* tbl4b = tbl4a + (size_t)(TBL+1)*32;         // (TBL+1)*32 float4
  float4* edata = tbl4b + (size_t)(TBL+1)*32;         // E float4
  int*    srcp  = (int*)(edata + (size_t)E_);         // E
  int*    deg   = srcp + E_;                          // N
  int*    off   = deg + N_;                           // N+1
  int*    cursor= off + N_ + 1;                       // N

  // layer-0 acc scratch: d_out (N*32 float4) — dead until final write.
  float4* acc4a = (float4*)d_out;

  int gathBlocks = (N_ + 3) / 4;
  int updBlocks  = (N_ + 7) / 8;
  int edgeBlocks = (E_ + 255) / 256;
  int nodeB32    = (N_ + 31) / 32;
  int tblB32     = (TBL + 1 + 31) / 32;

  // --- CSR hist ---
  hipMemsetAsync(deg, 0, (size_t)N_ * sizeof(int), stream);
  hist_kernel<<<edgeBlocks, 256, 0, stream>>>(ei, deg, E_);

  // --- scan + nodeA(l0) + tbl(l0) + tbl(l1), one launch ---
  scan_prep_kernel<<<1 + nodeB32 + 2*tblB32, 1024, 0, stream>>>(
      deg, off, cursor, N_, s_in,
      mp_w1, mp_b1, mp_w2, mp_b2,
      mw_w1, mw_b1, mw_w2, mw_b2,
      mw_w1 + 1024, mw_b1 + 32, mw_w2 + 4096, mw_b2 + 128,
      Aout4a, tbl4a, tbl4b, nodeB32, tblB32);

  // --- CSR data scatter ---
  scatter_kernel<<<edgeBlocks, 256, 0, stream>>>(ei, dist, edir, cursor, srcp, edata, E_);

  // --- layer 0 ---
  gather_kernel<<<gathBlocks, 256, 0, stream>>>(
      off, srcp, edata, tbl4a, v_in, Aout4a, acc4a, N_);
  update_mid_kernel<<<updBlocks, 256, 0, stream>>>(
      s_in, v_in, acc4a,
      u_U, u_V, u_w1, u_b1, u_w2, u_b2,
      mp_w1 + 1024, mp_b1 + 32, mp_w2 + 4096, mp_b2 + 128,
      sB, vB, Aout4b, N_);

  // --- layer 1 ---
  gather_kernel<<<gathBlocks, 256, 0, stream>>>(
      off, srcp, edata, tbl4b, vB, Aout4b, acc4b, N_);
  update_fin_kernel<<<updBlocks, 256, 0, stream>>>(
      sB, vB, acc4b,
      u_U + 1024, u_V + 1024, u_w1 + 2048, u_b1 + 32, u_w2 + 3072, u_b2 + 96,
      ro_w1, ro_b1, ro_w2, ro_b2, ro_V, (float*)d_out, N_);
}

// Round 14
// 552.996 us; speedup vs baseline: 1.0603x; 1.0603x over previous
//
#include <hip/hip_runtime.h>
#include <math.h>

#define PI_LEN 0.3141592653589793f   // pi / 10.0
#define LEN_F  10.0f
#define TBL    4096                   // table rows = TBL+1

__device__ __forceinline__ float fsilu(float x) {
  return x * __builtin_amdgcn_rcpf(1.f + __expf(-x));
}

// ---------------------------------------------------------------------------
// hist: deg[dst]++
// ---------------------------------------------------------------------------
__global__ __launch_bounds__(256) void hist_kernel(const int* __restrict__ ei,
                                                   int* __restrict__ deg, int E_) {
  int e = blockIdx.x * 256 + threadIdx.x;
  if (e < E_) atomicAdd(&deg[ei[E_ + e]], 1);
}

// ---------------------------------------------------------------------------
// tbl role helper (32 t-rows / 1024-thread block; half-wave-private LDS rows)
// ---------------------------------------------------------------------------
__device__ __forceinline__ void tbl_role(
    int i, int g, int t,
    const float* __restrict__ w1, const float* __restrict__ b1,
    const float* __restrict__ w2, const float* __restrict__ b2,
    float4* __restrict__ tbl4, float (*pe)[32], float (*hl)[32])
{
  bool okt = (t <= TBL);
  float d = (float)t * (LEN_F / (float)TBL);
  pe[i][g] = (g < 16) ? __sinf(d * (float)(g + 1) * PI_LEN)
                      : __cosf(d * (float)(g - 15) * PI_LEN);
  float h = b1[g];
  for (int k = 0; k < 32; ++k) h += pe[i][k] * w1[k*32 + g];
  hl[i][g] = fsilu(h);
  float o0 = b2[g], o1 = b2[32+g], o2 = b2[64+g], o3 = b2[96+g];
  for (int k = 0; k < 32; ++k) {
    float hk = hl[i][k];
    o0 += hk * w2[k*128 +      g];
    o1 += hk * w2[k*128 + 32 + g];
    o2 += hk * w2[k*128 + 64 + g];
    o3 += hk * w2[k*128 + 96 + g];
  }
  if (okt) tbl4[(long)t*32 + g] = make_float4(o0, o1, o2, o3);
}

// ---------------------------------------------------------------------------
// scan + prep roles in ONE launch:
//   block 0       -> exclusive scan of deg -> off, cursor
//   next nodeB32  -> nodeA(l0): Aout4a from s_in
//   next tblB32   -> filter table l0
//   next tblB32   -> filter table l1
// ---------------------------------------------------------------------------
__global__ __launch_bounds__(1024) void scan_prep_kernel(
    const int* __restrict__ deg, int* __restrict__ off,
    int* __restrict__ cursor, int N_,
    const float* __restrict__ s,
    const float* __restrict__ mpw1, const float* __restrict__ mpb1,
    const float* __restrict__ mpw2, const float* __restrict__ mpb2,
    const float* __restrict__ mww1a, const float* __restrict__ mwb1a,
    const float* __restrict__ mww2a, const float* __restrict__ mwb2a,
    const float* __restrict__ mww1b, const float* __restrict__ mwb1b,
    const float* __restrict__ mww2b, const float* __restrict__ mwb2b,
    float4* __restrict__ Aout4a, float4* __restrict__ tbl4a,
    float4* __restrict__ tbl4b, int nodeB32, int tblB32)
{
  __shared__ float xs[32][32];
  __shared__ float hs[32][32];
  __shared__ int wtot[16];
  __shared__ int carry_s;
  int bid = blockIdx.x;
  int tid = threadIdx.x;
  if (bid == 0) {                            // ---- scan role ----
    int lane = tid & 63, wid = tid >> 6;
    if (tid == 0) carry_s = 0;
    __syncthreads();
    int nch = (N_ + 8191) / 8192;
    for (int c = 0; c < nch; ++c) {
      int base_idx = c * 8192 + tid * 8;
      int x[8]; int mysum = 0;
      #pragma unroll
      for (int j = 0; j < 8; ++j) { int idx = base_idx + j; x[j] = (idx < N_) ? deg[idx] : 0; mysum += x[j]; }
      int incl = mysum;
      #pragma unroll
      for (int st = 1; st < 64; st <<= 1) { int t = __shfl_up(incl, st, 64); if (lane >= st) incl += t; }
      if (lane == 63) wtot[wid] = incl;
      __syncthreads();
      if (wid == 0) {
        int wt = (lane < 16) ? wtot[lane] : 0;
        #pragma unroll
        for (int st = 1; st < 16; st <<= 1) { int t = __shfl_up(wt, st, 64); if (lane >= st) wt += t; }
        if (lane < 16) wtot[lane] = wt;
      }
      __syncthreads();
      int wexcl = (wid > 0) ? wtot[wid - 1] : 0;
      int run = carry_s + wexcl + (incl - mysum);
      #pragma unroll
      for (int j = 0; j < 8; ++j) {
        int idx = base_idx + j;
        if (idx < N_) { off[idx] = run; cursor[idx] = run; }
        run += x[j];
      }
      __syncthreads();
      if (tid == 0) carry_s += wtot[15];
      __syncthreads();
    }
    if (tid == 0) off[N_] = carry_s;
    return;
  }
  bid -= 1;
  int i = tid >> 5, g = tid & 31;
  if (bid < nodeB32) {                       // ---- nodeA(l0) role ----
    long n = (long)bid * 32 + i;
    bool ok = (n < N_);
    xs[i][g] = ok ? s[n*32 + g] : 0.f;
    float h = mpb1[g];
    for (int k = 0; k < 32; ++k) h += xs[i][k] * mpw1[k*32 + g];
    hs[i][g] = fsilu(h);
    float o0 = mpb2[g], o1 = mpb2[32+g], o2 = mpb2[64+g], o3 = mpb2[96+g];
    for (int k = 0; k < 32; ++k) {
      float hk = hs[i][k];
      o0 += hk * mpw2[k*128 +      g];
      o1 += hk * mpw2[k*128 + 32 + g];
      o2 += hk * mpw2[k*128 + 64 + g];
      o3 += hk * mpw2[k*128 + 96 + g];
    }
    if (ok) Aout4a[n*32 + g] = make_float4(o0, o1, o2, o3 * xs[i][g]);
    return;
  }
  bid -= nodeB32;
  if (bid < tblB32) {                        // ---- tbl l0 role ----
    tbl_role(i, g, bid * 32 + i, mww1a, mwb1a, mww2a, mwb2a, tbl4a, xs, hs);
    return;
  }
  bid -= tblB32;                             // ---- tbl l1 role ----
  tbl_role(i, g, bid * 32 + i, mww1b, mwb1b, mww2b, mwb2b, tbl4b, xs, hs);
}

// ---------------------------------------------------------------------------
// scatter: CSR data perm (after scan)
// ---------------------------------------------------------------------------
__global__ __launch_bounds__(256) void scatter_kernel(
    const int* __restrict__ ei, const float* __restrict__ dist,
    const float* __restrict__ edir, int* __restrict__ cursor,
    int* __restrict__ srcp, float4* __restrict__ edata, int E_) {
  int e = blockIdx.x * 256 + threadIdx.x;
  if (e < E_) {
    int dst = ei[E_ + e];
    int pos = atomicAdd(&cursor[dst], 1);
    srcp[pos] = ei[e];
    edata[pos] = make_float4(edir[3*e], edir[3*e+1], edir[3*e+2], dist[e]);
  }
}

// ---------------------------------------------------------------------------
// gather: EXACT round-4 proven shape (56 VGPR, no LDS, no barriers).
// ---------------------------------------------------------------------------
#define EDGE_MATH(ED, M0, M1, FR, Av, V0, V1, V2)                         \
  {                                                                        \
    float ga = M0.x + FR*(M1.x - M0.x);                                    \
    float ca = M0.y + FR*(M1.y - M0.y);                                    \
    float da = M0.z + FR*(M1.z - M0.z);                                    \
    float sa = M0.w + FR*(M1.w - M0.w);                                    \
    float gates = ga*Av.x, cpg = ca*Av.y, sed = da*Av.z;                   \
    acc_s += sa*Av.w;                                                      \
    float crx = ED.y*vd2 - ED.z*vd1;                                       \
    float cry = ED.z*vd0 - ED.x*vd2;                                       \
    float crz = ED.x*vd1 - ED.y*vd0;                                       \
    av0 += sed*ED.x + gates*V0 + cpg*crx;                                  \
    av1 += sed*ED.y + gates*V1 + cpg*cry;                                  \
    av2 += sed*ED.z + gates*V2 + cpg*crz;                                  \
  }

__global__ __launch_bounds__(256) void gather_kernel(
    const int* __restrict__ off, const int* __restrict__ srcp,
    const float4* __restrict__ edata, const float4* __restrict__ tbl4,
    const float* __restrict__ v_prev, const float4* __restrict__ Aout4,
    float4* __restrict__ acc4, int N_)
{
  int tid = threadIdx.x, w = tid >> 6, lane = tid & 63, g = lane & 31, hf = lane >> 5;
  int n = blockIdx.x * 4 + w;
  if (n >= N_) return;
  const float* vp = v_prev + (long)n*96 + g*3;
  float vd0 = vp[0], vd1 = vp[1], vd2 = vp[2];
  int pstart = off[n], pend = off[n + 1];
  float acc_s = 0, av0 = 0, av1 = 0, av2 = 0;
  const float inv_step = (float)TBL / LEN_F;

  int deg = pend - pstart;
  int nfull = deg >> 3;
  int pb = pstart + hf * 4;
  for (int it = 0; it < nfull; ++it, pb += 8) {
    int srcs[4]; float4 ed[4];
    #pragma unroll
    for (int b = 0; b < 4; ++b) { srcs[b] = srcp[pb + b]; ed[b] = edata[pb + b]; }
    float4 m0[4], m1[4], A[4]; float fr[4];
    float vs0[4], vs1[4], vs2[4];
    #pragma unroll
    for (int b = 0; b < 4; ++b) {
      float x = ed[b].w * inv_step;
      float f = floorf(x);
      int i0 = (int)f; if (i0 > TBL - 1) i0 = TBL - 1;
      fr[b] = x - f;
      m0[b] = tbl4[(long)i0*32 + g];
      m1[b] = tbl4[(long)(i0 + 1)*32 + g];
      A[b]  = Aout4[(long)srcs[b]*32 + g];
      const float* vq = v_prev + (long)srcs[b]*96 + g*3;
      vs0[b] = vq[0]; vs1[b] = vq[1]; vs2[b] = vq[2];
    }
    #pragma unroll
    for (int b = 0; b < 4; ++b)
      EDGE_MATH(ed[b], m0[b], m1[b], fr[b], A[b], vs0[b], vs1[b], vs2[b]);
  }
  int p = pstart + nfull * 8 + hf;
  for (; p + 2 < pend; p += 4) {
    int  s0_ = srcp[p], s1_ = srcp[p + 2];
    float4 e0 = edata[p], e1 = edata[p + 2];
    float x0 = e0.w * inv_step, x1 = e1.w * inv_step;
    float f0 = floorf(x0), f1 = floorf(x1);
    int i0 = (int)f0; if (i0 > TBL - 1) i0 = TBL - 1;
    int i1 = (int)f1; if (i1 > TBL - 1) i1 = TBL - 1;
    float r0 = x0 - f0, r1 = x1 - f1;
    float4 a0 = tbl4[(long)i0*32 + g], b0 = tbl4[(long)(i0+1)*32 + g];
    float4 a1 = tbl4[(long)i1*32 + g], b1 = tbl4[(long)(i1+1)*32 + g];
    float4 A0 = Aout4[(long)s0_*32 + g], A1 = Aout4[(long)s1_*32 + g];
    const float* vq0 = v_prev + (long)s0_*96 + g*3;
    const float* vq1 = v_prev + (long)s1_*96 + g*3;
    float u0 = vq0[0], u1 = vq0[1], u2 = vq0[2];
    float t0 = vq1[0], t1 = vq1[1], t2 = vq1[2];
    EDGE_MATH(e0, a0, b0, r0, A0, u0, u1, u2);
    EDGE_MATH(e1, a1, b1, r1, A1, t0, t1, t2);
  }
  if (p < pend) {
    int  s0_ = srcp[p];
    float4 e0 = edata[p];
    float x0 = e0.w * inv_step;
    float f0 = floorf(x0);
    int i0 = (int)f0; if (i0 > TBL - 1) i0 = TBL - 1;
    float r0 = x0 - f0;
    float4 a0 = tbl4[(long)i0*32 + g], b0 = tbl4[(long)(i0+1)*32 + g];
    float4 A0 = Aout4[(long)s0_*32 + g];
    const float* vq0 = v_prev + (long)s0_*96 + g*3;
    float u0 = vq0[0], u1 = vq0[1], u2 = vq0[2];
    EDGE_MATH(e0, a0, b0, r0, A0, u0, u1, u2);
  }
  av0   += __shfl_xor(av0, 32);
  av1   += __shfl_xor(av1, 32);
  av2   += __shfl_xor(av2, 32);
  acc_s += __shfl_xor(acc_s, 32);
  if (hf == 0) acc4[(long)n*32 + g] = make_float4(av0, av1, av2, acc_s);
}

// ---------------------------------------------------------------------------
// update kernels: r11 proven shape — 2 nodes per wave, weight loads shared
// x2 via dual accumulation, k-split across halves + shfl_xor(32),
// barrier-free per-wave LDS rows (stride-3 v staging, measured optimum).
// ---------------------------------------------------------------------------
__global__ __launch_bounds__(256) void update_mid_kernel(
    const float* __restrict__ s_prev, const float* __restrict__ v_prev,
    const float4* __restrict__ acc4,
    const float* __restrict__ uU, const float* __restrict__ uV,
    const float* __restrict__ uw1, const float* __restrict__ ub1,
    const float* __restrict__ uw2, const float* __restrict__ ub2,
    const float* __restrict__ nw1, const float* __restrict__ nb1,
    const float* __restrict__ nw2, const float* __restrict__ nb2,
    float* __restrict__ s_out, float* __restrict__ v_out,
    float4* __restrict__ Aout4b, int N_)
{
  __shared__ float vA_[4][96], vB_[4][96];
  __shared__ float inA[4][64], inB[4][64];
  __shared__ float hA_[4][32], hB_[4][32];
  int tid = threadIdx.x, w = tid >> 6, lane = tid & 63, g = lane & 31, hf = lane >> 5;
  long nown = (long)blockIdx.x * 8 + 2*w + hf;
  bool ok = (nown < N_);
  float nv0 = 0, nv1 = 0, nv2 = 0, ns = 0;
  if (ok) {
    float4 a = acc4[nown*32 + g];
    const float* vp = v_prev + nown*96 + g*3;
    nv0 = vp[0] + a.x; nv1 = vp[1] + a.y; nv2 = vp[2] + a.z;
    ns  = s_prev[nown*32 + g] + a.w;
  }
  if (hf == 0) {
    vA_[w][g*3+0] = nv0; vA_[w][g*3+1] = nv1; vA_[w][g*3+2] = nv2;
    inA[w][32+g] = ns;
  } else {
    vB_[w][g*3+0] = nv0; vB_[w][g*3+1] = nv1; vB_[w][g*3+2] = nv2;
    inB[w][32+g] = ns;
  }
  float VvA0=0,VvA1=0,VvA2=0,UvA0=0,UvA1=0,UvA2=0;
  float VvB0=0,VvB1=0,VvB2=0,UvB0=0,UvB1=0,UvB2=0;
  for (int j = 0; j < 16; ++j) {
    int k = hf*16 + j;
    float wv = uV[k*32 + g], wu = uU[k*32 + g];
    float a0 = vA_[w][k*3+0], a1 = vA_[w][k*3+1], a2 = vA_[w][k*3+2];
    float b0 = vB_[w][k*3+0], b1 = vB_[w][k*3+1], b2 = vB_[w][k*3+2];
    VvA0 += a0*wv; VvA1 += a1*wv; VvA2 += a2*wv;
    UvA0 += a0*wu; UvA1 += a1*wu; UvA2 += a2*wu;
    VvB0 += b0*wv; VvB1 += b1*wv; VvB2 += b2*wv;
    UvB0 += b0*wu; UvB1 += b1*wu; UvB2 += b2*wu;
  }
  VvA0 += __shfl_xor(VvA0,32); VvA1 += __shfl_xor(VvA1,32); VvA2 += __shfl_xor(VvA2,32);
  UvA0 += __shfl_xor(UvA0,32); UvA1 += __shfl_xor(UvA1,32); UvA2 += __shfl_xor(UvA2,32);
  VvB0 += __shfl_xor(VvB0,32); VvB1 += __shfl_xor(VvB1,32); VvB2 += __shfl_xor(VvB2,32);
  UvB0 += __shfl_xor(UvB0,32); UvB1 += __shfl_xor(UvB1,32); UvB2 += __shfl_xor(UvB2,32);
  float VnA = sqrtf(VvA0*VvA0 + VvA1*VvA1 + VvA2*VvA2);
  float VnB = sqrtf(VvB0*VvB0 + VvB1*VvB1 + VvB2*VvB2);
  float Vno = hf ? VnB : VnA;
  float Uv0 = hf ? UvB0 : UvA0, Uv1 = hf ? UvB1 : UvA1, Uv2 = hf ? UvB2 : UvA2;
  if (hf == 0) inA[w][g] = VnA; else inB[w][g] = VnB;
  float hAa = 0, hBb = 0;
  for (int j = 0; j < 32; ++j) {
    int k = hf*32 + j;
    float wk = uw1[k*32 + g];
    hAa += inA[w][k]*wk; hBb += inB[w][k]*wk;
  }
  hAa += __shfl_xor(hAa, 32); hBb += __shfl_xor(hBb, 32);
  float bb1 = ub1[g];
  hAa = fsilu(hAa + bb1); hBb = fsilu(hBb + bb1);
  if (hf == 0) hA_[w][g] = hAa; else hB_[w][g] = hBb;
  float ogA=0, osA=0, oaA=0, ogB=0, osB=0, oaB=0;
  for (int j = 0; j < 16; ++j) {
    int k = hf*16 + j;
    float w0 = uw2[k*96 + g], w1 = uw2[k*96 + 32 + g], w2 = uw2[k*96 + 64 + g];
    float ha = hA_[w][k], hb = hB_[w][k];
    ogA += ha*w0; osA += ha*w1; oaA += ha*w2;
    ogB += hb*w0; osB += hb*w1; oaB += hb*w2;
  }
  ogA += __shfl_xor(ogA,32); osA += __shfl_xor(osA,32); oaA += __shfl_xor(oaA,32);
  ogB += __shfl_xor(ogB,32); osB += __shfl_xor(osB,32); oaB += __shfl_xor(oaB,32);
  float og_o = (hf ? ogB : ogA) + ub2[g];
  float os_o = (hf ? osB : osA) + ub2[32 + g];
  float oa_o = (hf ? oaB : oaA) + ub2[64 + g];
  float sfin = ns + Vno*Vno*os_o + oa_o;
  if (ok) {
    float* vo = v_out + nown*96 + g*3;
    vo[0] = nv0 + og_o*Uv0;
    vo[1] = nv1 + og_o*Uv1;
    vo[2] = nv2 + og_o*Uv2;
    s_out[nown*32 + g] = sfin;
  }
  if (hf == 0) inA[w][g] = sfin; else inB[w][g] = sfin;
  float h2A = 0, h2B = 0;
  for (int j = 0; j < 16; ++j) {
    int k = hf*16 + j;
    float wk = nw1[k*32 + g];
    h2A += inA[w][k]*wk; h2B += inB[w][k]*wk;
  }
  h2A += __shfl_xor(h2A, 32); h2B += __shfl_xor(h2B, 32);
  float nb1g = nb1[g];
  h2A = fsilu(h2A + nb1g); h2B = fsilu(h2B + nb1g);
  if (hf == 0) hA_[w][g] = h2A; else hB_[w][g] = h2B;
  float o0A=0,o1A=0,o2A=0,o3A=0, o0B=0,o1B=0,o2B=0,o3B=0;
  for (int j = 0; j < 16; ++j) {
    int k = hf*16 + j;
    float w0 = nw2[k*128 + g],      w1 = nw2[k*128 + 32 + g];
    float w2 = nw2[k*128 + 64 + g], w3 = nw2[k*128 + 96 + g];
    float ha = hA_[w][k], hb = hB_[w][k];
    o0A += ha*w0; o1A += ha*w1; o2A += ha*w2; o3A += ha*w3;
    o0B += hb*w0; o1B += hb*w1; o2B += hb*w2; o3B += hb*w3;
  }
  o0A += __shfl_xor(o0A,32); o1A += __shfl_xor(o1A,32);
  o2A += __shfl_xor(o2A,32); o3A += __shfl_xor(o3A,32);
  o0B += __shfl_xor(o0B,32); o1B += __shfl_xor(o1B,32);
  o2B += __shfl_xor(o2B,32); o3B += __shfl_xor(o3B,32);
  float o0o = (hf ? o0B : o0A) + nb2[g];
  float o1o = (hf ? o1B : o1A) + nb2[32 + g];
  float o2o = (hf ? o2B : o2A) + nb2[64 + g];
  float o3o = (hf ? o3B : o3A) + nb2[96 + g];
  if (ok) Aout4b[nown*32 + g] = make_float4(o0o, o1o, o2o, o3o * sfin);
}

__global__ __launch_bounds__(256) void update_fin_kernel(
    const float* __restrict__ s_prev, const float* __restrict__ v_prev,
    const float4* __restrict__ acc4,
    const float* __restrict__ uU, const float* __restrict__ uV,
    const float* __restrict__ uw1, const float* __restrict__ ub1,
    const float* __restrict__ uw2, const float* __restrict__ ub2,
    const float* __restrict__ rw1, const float* __restrict__ rb1,
    const float* __restrict__ rw2, const float* __restrict__ rb2,
    const float* __restrict__ roV, float* __restrict__ out, int N_)
{
  __shared__ float vA_[4][96], vB_[4][96];
  __shared__ float inA[4][64], inB[4][64];
  __shared__ float hA_[4][32], hB_[4][32];
  int tid = threadIdx.x, w = tid >> 6, lane = tid & 63, g = lane & 31, hf = lane >> 5;
  long nown = (long)blockIdx.x * 8 + 2*w + hf;
  bool ok = (nown < N_);
  float nv0 = 0, nv1 = 0, nv2 = 0, ns = 0;
  if (ok) {
    float4 a = acc4[nown*32 + g];
    const float* vp = v_prev + nown*96 + g*3;
    nv0 = vp[0] + a.x; nv1 = vp[1] + a.y; nv2 = vp[2] + a.z;
    ns  = s_prev[nown*32 + g] + a.w;
  }
  if (hf == 0) {
    vA_[w][g*3+0] = nv0; vA_[w][g*3+1] = nv1; vA_[w][g*3+2] = nv2;
    inA[w][32+g] = ns;
  } else {
    vB_[w][g*3+0] = nv0; vB_[w][g*3+1] = nv1; vB_[w][g*3+2] = nv2;
    inB[w][32+g] = ns;
  }
  float VvA0=0,VvA1=0,VvA2=0,UvA0=0,UvA1=0,UvA2=0;
  float VvB0=0,VvB1=0,VvB2=0,UvB0=0,UvB1=0,UvB2=0;
  for (int j = 0; j < 16; ++j) {
    int k = hf*16 + j;
    float wv = uV[k*32 + g], wu = uU[k*32 + g];
    float a0 = vA_[w][k*3+0], a1 = vA_[w][k*3+1], a2 = vA_[w][k*3+2];
    float b0 = vB_[w][k*3+0], b1 = vB_[w][k*3+1], b2 = vB_[w][k*3+2];
    VvA0 += a0*wv; VvA1 += a1*wv; VvA2 += a2*wv;
    UvA0 += a0*wu; UvA1 += a1*wu; UvA2 += a2*wu;
    VvB0 += b0*wv; VvB1 += b1*wv; VvB2 += b2*wv;
    UvB0 += b0*wu; UvB1 += b1*wu; UvB2 += b2*wu;
  }
  VvA0 += __shfl_xor(VvA0,32); VvA1 += __shfl_xor(VvA1,32); VvA2 += __shfl_xor(VvA2,32);
  UvA0 += __shfl_xor(UvA0,32); UvA1 += __shfl_xor(UvA1,32); UvA2 += __shfl_xor(UvA2,32);
  VvB0 += __shfl_xor(VvB0,32); VvB1 += __shfl_xor(VvB1,32); VvB2 += __shfl_xor(VvB2,32);
  UvB0 += __shfl_xor(UvB0,32); UvB1 += __shfl_xor(UvB1,32); UvB2 += __shfl_xor(UvB2,32);
  float VnA = sqrtf(VvA0*VvA0 + VvA1*VvA1 + VvA2*VvA2);
  float VnB = sqrtf(VvB0*VvB0 + VvB1*VvB1 + VvB2*VvB2);
  float Vno = hf ? VnB : VnA;
  float Uv0 = hf ? UvB0 : UvA0, Uv1 = hf ? UvB1 : UvA1, Uv2 = hf ? UvB2 : UvA2;
  if (hf == 0) inA[w][g] = VnA; else inB[w][g] = VnB;
  float hAa = 0, hBb = 0;
  for (int j = 0; j < 32; ++j) {
    int k = hf*32 + j;
    float wk = uw1[k*32 + g];
    hAa += inA[w][k]*wk; hBb += inB[w][k]*wk;
  }
  hAa += __shfl_xor(hAa, 32); hBb += __shfl_xor(hBb, 32);
  float bb1 = ub1[g];
  hAa = fsilu(hAa + bb1); hBb = fsilu(hBb + bb1);
  if (hf == 0) hA_[w][g] = hAa; else hB_[w][g] = hBb;
  float ogA=0, osA=0, oaA=0, ogB=0, osB=0, oaB=0;
  for (int j = 0; j < 16; ++j) {
    int k = hf*16 + j;
    float w0 = uw2[k*96 + g], w1 = uw2[k*96 + 32 + g], w2 = uw2[k*96 + 64 + g];
    float ha = hA_[w][k], hb = hB_[w][k];
    ogA += ha*w0; osA += ha*w1; oaA += ha*w2;
    ogB += hb*w0; osB += hb*w1; oaB += hb*w2;
  }
  ogA += __shfl_xor(ogA,32); osA += __shfl_xor(osA,32); oaA += __shfl_xor(oaA,32);
  ogB += __shfl_xor(ogB,32); osB += __shfl_xor(osB,32); oaB += __shfl_xor(oaB,32);
  float og_o = (hf ? ogB : ogA) + ub2[g];
  float os_o = (hf ? osB : osA) + ub2[32 + g];
  float oa_o = (hf ? oaB : oaA) + ub2[64 + g];
  float sfin = ns + Vno*Vno*os_o + oa_o;
  float vf0 = nv0 + og_o*Uv0, vf1 = nv1 + og_o*Uv1, vf2 = nv2 + og_o*Uv2;
  if (hf == 0) {
    vA_[w][g*3+0] = vf0; vA_[w][g*3+1] = vf1; vA_[w][g*3+2] = vf2;
    inA[w][g] = sfin;
  } else {
    vB_[w][g*3+0] = vf0; vB_[w][g*3+1] = vf1; vB_[w][g*3+2] = vf2;
    inB[w][g] = sfin;
  }
  float h2A = 0, h2B = 0;
  for (int j = 0; j < 16; ++j) {
    int k = hf*16 + j;
    float wk = rw1[k*32 + g];
    h2A += inA[w][k]*wk; h2B += inB[w][k]*wk;
  }
  h2A += __shfl_xor(h2A, 32); h2B += __shfl_xor(h2B, 32);
  float rb1g = rb1[g];
  h2A = fsilu(h2A + rb1g); h2B = fsilu(h2B + rb1g);
  if (hf == 0) hA_[w][g] = h2A; else hB_[w][g] = h2B;
  float invA=0, gateA=0, invB=0, gateB=0;
  for (int j = 0; j < 16; ++j) {
    int k = hf*16 + j;
    float w0 = rw2[k*64 + g], w1 = rw2[k*64 + 32 + g];
    float ha = hA_[w][k], hb = hB_[w][k];
    invA += ha*w0; gateA += ha*w1;
    invB += hb*w0; gateB += hb*w1;
  }
  float R0A=0,R1A=0,R2A=0, R0B=0,R1B=0,R2B=0;
  for (int j = 0; j < 16; ++j) {
    int k = hf*16 + j;
    float wk = roV[k*32 + g];
    R0A += vA_[w][k*3+0]*wk; R1A += vA_[w][k*3+1]*wk; R2A += vA_[w][k*3+2]*wk;
    R0B += vB_[w][k*3+0]*wk; R1B += vB_[w][k*3+1]*wk; R2B += vB_[w][k*3+2]*wk;
  }
  invA += __shfl_xor(invA,32); gateA += __shfl_xor(gateA,32);
  invB += __shfl_xor(invB,32); gateB += __shfl_xor(gateB,32);
  R0A += __shfl_xor(R0A,32); R1A += __shfl_xor(R1A,32); R2A += __shfl_xor(R2A,32);
  R0B += __shfl_xor(R0B,32); R1B += __shfl_xor(R1B,32); R2B += __shfl_xor(R2B,32);
  float inv_o  = (hf ? invB  : invA)  + rb2[g];
  float gate_o = (hf ? gateB : gateA) + rb2[32 + g];
  float R0o = hf ? R0B : R0A, R1o = hf ? R1B : R1A, R2o = hf ? R2B : R2A;
  if (ok) {
    out[nown*32 + g] = inv_o;
    long eb = (long)N_*32 + nown*96 + (long)g*3;
    out[eb+0] = gate_o*R0o; out[eb+1] = gate_o*R1o; out[eb+2] = gate_o*R2o;
  }
}

// ---------------------------------------------------------------------------
extern "C" void kernel_launch(void* const* d_in, const int* in_sizes, int n_in,
                              void* d_out, int out_size, void* d_ws, size_t ws_size,
                              hipStream_t stream)
{
  const float* s_in  = (const float*)d_in[0];
  const float* v_in  = (const float*)d_in[1];   // (N, F, 3)
  const int*   ei    = (const int*)  d_in[2];
  const float* dist  = (const float*)d_in[3];
  const float* edir  = (const float*)d_in[4];
  const float* mp_w1 = (const float*)d_in[5];
  const float* mp_b1 = (const float*)d_in[6];
  const float* mp_w2 = (const float*)d_in[7];
  const float* mp_b2 = (const float*)d_in[8];
  const float* mw_w1 = (const float*)d_in[9];
  const float* mw_b1 = (const float*)d_in[10];
  const float* mw_w2 = (const float*)d_in[11];
  const float* mw_b2 = (const float*)d_in[12];
  const float* u_U   = (const float*)d_in[13];
  const float* u_V   = (const float*)d_in[14];
  const float* u_w1  = (const float*)d_in[15];
  const float* u_b1  = (const float*)d_in[16];
  const float* u_w2  = (const float*)d_in[17];
  const float* u_b2  = (const float*)d_in[18];
  const float* ro_w1 = (const float*)d_in[19];
  const float* ro_b1 = (const float*)d_in[20];
  const float* ro_w2 = (const float*)d_in[21];
  const float* ro_b2 = (const float*)d_in[22];
  const float* ro_V  = (const float*)d_in[23];

  int N_ = in_sizes[0] / 32;
  int E_ = in_sizes[3];

  float*  sB    = (float*)d_ws;                       // N*32
  float*  vB    = sB + (size_t)N_*32;                 // N*96
  float4* Aout4a= (float4*)(vB + (size_t)N_*96);      // N*32 float4
  float4* Aout4b= Aout4a + (size_t)N_*32;             // N*32 float4
  float4* acc4b = Aout4b + (size_t)N_*32;             // N*32 float4
  float4* tbl4a = acc4b + (size_t)N_*32;              // (TBL+1)*32 float4
  float4* tbl4b = tbl4a + (size_t)(TBL+1)*32;         // (TBL+1)*32 float4
  float4* edata = tbl4b + (size_t)(TBL+1)*32;         // E float4
  int*    srcp  = (int*)(edata + (size_t)E_);         // E
  int*    deg   = srcp + E_;                          // N
  int*    off   = deg + N_;                           // N+1
  int*    cursor= off + N_ + 1;                       // N

  // layer-0 acc scratch: d_out (N*32 float4) — dead until final write.
  float4* acc4a = (float4*)d_out;

  int gathBlocks = (N_ + 3) / 4;
  int updBlocks  = (N_ + 7) / 8;
  int edgeBlocks = (E_ + 255) / 256;
  int nodeB32    = (N_ + 31) / 32;
  int tblB32     = (TBL + 1 + 31) / 32;

  // --- CSR hist ---
  hipMemsetAsync(deg, 0, (size_t)N_ * sizeof(int), stream);
  hist_kernel<<<edgeBlocks, 256, 0, stream>>>(ei, deg, E_);

  // --- scan + nodeA(l0) + tbl(l0) + tbl(l1), one launch ---
  scan_prep_kernel<<<1 + nodeB32 + 2*tblB32, 1024, 0, stream>>>(
      deg, off, cursor, N_, s_in,
      mp_w1, mp_b1, mp_w2, mp_b2,
      mw_w1, mw_b1, mw_w2, mw_b2,
      mw_w1 + 1024, mw_b1 + 32, mw_w2 + 4096, mw_b2 + 128,
      Aout4a, tbl4a, tbl4b, nodeB32, tblB32);

  // --- CSR data scatter ---
  scatter_kernel<<<edgeBlocks, 256, 0, stream>>>(ei, dist, edir, cursor, srcp, edata, E_);

  // --- layer 0 ---
  gather_kernel<<<gathBlocks, 256, 0, stream>>>(
      off, srcp, edata, tbl4a, v_in, Aout4a, acc4a, N_);
  update_mid_kernel<<<updBlocks, 256, 0, stream>>>(
      s_in, v_in, acc4a,
      u_U, u_V, u_w1, u_b1, u_w2, u_b2,
      mp_w1 + 1024, mp_b1 + 32, mp_w2 + 4096, mp_b2 + 128,
      sB, vB, Aout4b, N_);

  // --- layer 1 ---
  gather_kernel<<<gathBlocks, 256, 0, stream>>>(
      off, srcp, edata, tbl4b, vB, Aout4b, acc4b, N_);
  update_fin_kernel<<<updBlocks, 256, 0, stream>>>(
      sB, vB, acc4b,
      u_U + 1024, u_V + 1024, u_w1 + 2048, u_b1 + 32, u_w2 + 3072, u_b2 + 96,
      ro_w1, ro_b1, ro_w2, ro_b2, ro_V, (float*)d_out, N_);
}